// Round 1
// baseline (964.234 us; speedup 1.0000x reference)
//
#include <hip/hip_runtime.h>

// snntorch Synaptic scan, reset_mechanism='zero'.
// T=512, B=32, N=4096. x: (T,B,N) f32. out: [spk | syn | mem], each (T,B,N) f32.
// Per step: keep = (mem_prev <= thr); syn' = a*syn + x; mem' = b*mem + syn';
//           syn' *= keep; mem' *= keep; spk = (mem' > thr).
// Numerics: __fmul_rn/__fadd_rn to forbid FMA contraction -> bit-match numpy
// fp32 reference (spk is binary; a flipped borderline spike = absmax 1.0).

#define T_STEPS 512
#define BN      131072          // 32*4096 elements per timestep
#define NT4     (BN / 4)        // 32768 float4 lanes

__global__ __launch_bounds__(64) void snn_synaptic_kernel(
    const float4* __restrict__ x, float* __restrict__ out) {
  const int i = blockIdx.x * 64 + threadIdx.x;   // 0 .. NT4-1

  float4* __restrict__ spk_o = (float4*)out;
  float4* __restrict__ syn_o = (float4*)(out + (long long)T_STEPS * BN);
  float4* __restrict__ mem_o = (float4*)(out + 2LL * T_STEPS * BN);

  float4 syn = make_float4(0.f, 0.f, 0.f, 0.f);
  float4 mem = make_float4(0.f, 0.f, 0.f, 0.f);

  // prefetch t=0
  float4 xc = x[i];

  #pragma unroll 4
  for (int t = 0; t < T_STEPS; ++t) {
    // prefetch next step's x (clamped: re-loads last slab once, harmless)
    const int tn = (t + 1 < T_STEPS) ? (t + 1) : t;
    float4 xn = x[(long long)tn * NT4 + i];

    float4 spk;
    #define STEP(c)                                                  \
      {                                                              \
        const float keep = (mem.c > 2.0f) ? 0.0f : 1.0f;             \
        syn.c = __fadd_rn(__fmul_rn(0.1f, syn.c), xc.c);             \
        mem.c = __fadd_rn(__fmul_rn(0.96f, mem.c), syn.c);           \
        syn.c *= keep;                                               \
        mem.c *= keep;                                               \
        spk.c = (mem.c > 2.0f) ? 1.0f : 0.0f;                        \
      }
    STEP(x) STEP(y) STEP(z) STEP(w)
    #undef STEP

    const long long o = (long long)t * NT4 + i;
    spk_o[o] = spk;
    syn_o[o] = syn;
    mem_o[o] = mem;

    xc = xn;
  }
}

extern "C" void kernel_launch(void* const* d_in, const int* in_sizes, int n_in,
                              void* d_out, int out_size, void* d_ws, size_t ws_size,
                              hipStream_t stream) {
  const float4* x = (const float4*)d_in[0];
  float* out = (float*)d_out;
  snn_synaptic_kernel<<<dim3(NT4 / 64), dim3(64), 0, stream>>>(x, out);
}